// Round 10
// baseline (210.949 us; speedup 1.0000x reference)
//
#include <hip/hip_runtime.h>
#include <stdint.h>

typedef __bf16 bf16x8 __attribute__((ext_vector_type(8)));
typedef float f32x4 __attribute__((ext_vector_type(4)));
typedef unsigned short u16x8 __attribute__((ext_vector_type(8)));

__device__ __forceinline__ unsigned short f2bf(float f) {
  uint32_t u = __builtin_bit_cast(uint32_t, f);
  u += 0x7FFFu + ((u >> 16) & 1u);   // RNE
  return (unsigned short)(u >> 16);
}
__device__ __forceinline__ float bf2f(unsigned short h) {
  uint32_t u = ((uint32_t)h) << 16;
  return __builtin_bit_cast(float, u);
}

__device__ __forceinline__ void gload_lds16(const void* g, void* l) {
  __builtin_amdgcn_global_load_lds(
      (const __attribute__((address_space(1))) uint32_t*)g,
      (__attribute__((address_space(3))) uint32_t*)l,
      16, 0, 0);
}

// ---------------- convert kernels ----------------

__global__ __launch_bounds__(256) void k_cvt_x(const float* __restrict__ x,
                                               unsigned short* __restrict__ xb, int n4) {
  int stride = gridDim.x * blockDim.x;
  for (int i = blockIdx.x * blockDim.x + threadIdx.x; i < n4; i += stride) {
    float4 v = reinterpret_cast<const float4*>(x)[i];
    ushort4 o;
    o.x = f2bf(v.x); o.y = f2bf(v.y); o.z = f2bf(v.z); o.w = f2bf(v.w);
    reinterpret_cast<ushort4*>(xb)[i] = o;
  }
}

// w: [K][N] f32  ->  wt: [N][K] bf16  (transpose + convert)
__global__ __launch_bounds__(256) void k_cvt_wT(const float* __restrict__ w,
                                                unsigned short* __restrict__ wt, int K, int N) {
  int total = K * N;
  int stride = gridDim.x * blockDim.x;
  for (int i = blockIdx.x * blockDim.x + threadIdx.x; i < total; i += stride) {
    int n = i / K;
    int k = i - n * K;
    wt[i] = f2bf(w[(size_t)k * N + n]);
  }
}

// ---- GEMM 128x128, BK=32, A-in-LDS (dbuf 16KB) + B-DIRECT-TO-REGS ----
// C[M,N] = A[M,512] * Bt[N,512]^T. 4 waves (2Mx2N), wave-tile 64x64.
// r9 diagnosis: LDS BW is the binding resource (192KB/round demand ~1920cyc
// vs matrix 1242cyc). Fix: B (L2-resident weight panel, XCD-swizzled) loads
// DIRECTLY global->regs, prefetched 1 K-tile ahead; lanes lk=0..3 share each
// 64B line (lane=lk*16+lr) so the gather fetches 1KB/instr, no amplification.
// LDS now holds only A: per-round 96KB (~960cyc) < matrix 1242cyc.
// 4 waves/SIMD (launch_bounds(256,4)); tile-end vmcnt(0)+barrier (drain is
// deterministic with mixed reg-loads; counted-vs-drain measured +-3%).
// A chunk swizzle slot^=(row>>1)&3 on BOTH stage source and ds_read.
// EPI==0: qkv epilogue (bf16 LDS-bounce scatter); EPI==1: f32 C + bias.
template <int EPI>
__global__ __launch_bounds__(256, 4) void k_gemm128(
    const unsigned short* __restrict__ A,
    const unsigned short* __restrict__ Bt,
    const float* __restrict__ bias,
    const float* __restrict__ brw,
    unsigned short* __restrict__ oq,
    unsigned short* __restrict__ okk,
    unsigned short* __restrict__ ov,
    float* __restrict__ of,
    int Ntiles) {
  __shared__ __align__(128) char lds[32768];  // A bufs [0,8K),[8K,16K); epilogue uses all 32K

  int cpx = gridDim.x >> 3;
  int bid = (blockIdx.x & 7) * cpx + (blockIdx.x >> 3);
  int bm = bid / Ntiles;
  int bn = bid - bm * Ntiles;
  int row0 = bm << 7;
  int col0 = bn << 7;
  int t = threadIdx.x;
  int lane = t & 63;
  int w = t >> 6;        // wave 0..3
  int wm = w >> 1;       // 0..1
  int wn = w & 1;        // 0..1
  int lr = lane & 15;
  int lk = lane >> 4;    // k-chunk 0..3

  const unsigned short* Ab = A + (size_t)row0 * 512;
  // per-lane B row pointer: row = col0 + wn*64 + nf*16 + lr, k offset lk*8
  const unsigned short* Bp = Bt + (size_t)(col0 + (wn << 6) + lr) * 512 + (lk << 3);

  f32x4 acc[4][4];
#pragma unroll
  for (int i = 0; i < 4; ++i)
#pragma unroll
    for (int j = 0; j < 4; ++j) acc[i][j] = f32x4{0.f, 0.f, 0.f, 0.f};

  // stage A K-tile kt into buffer kt&1: 2 gload_lds/thread (8KB total)
  auto stageA = [&](int kt) {
    int k0 = kt << 5;
    char* base = lds + ((kt & 1) << 13);
#pragma unroll
    for (int i = 0; i < 2; ++i) {
      int o = (i << 8) + t;          // chunk 0..511
      int row = o >> 2;              // 0..127
      int slot = o & 3;
      int gk = k0 + ((slot ^ ((row >> 1) & 3)) << 3);
      gload_lds16(Ab + (size_t)row * 512 + gk, base + (o << 4));
    }
  };

  // load B K-tile kt fragments into regs (4 x global b128, L2-resident)
  auto loadB = [&](int kt, bf16x8* dst) {
    const unsigned short* p = Bp + (kt << 5);
#pragma unroll
    for (int nf = 0; nf < 4; ++nf)
      dst[nf] = *reinterpret_cast<const bf16x8*>(p + ((size_t)nf << 13));  // nf*16 rows * 512
  };

  bf16x8 bcur[4], bnext[4];

  // prologue: stage A(0), load B(0)
  stageA(0);
  loadB(0, bcur);
  asm volatile("s_waitcnt vmcnt(0)" ::: "memory");
  __builtin_amdgcn_s_barrier();

#pragma unroll 1
  for (int kt = 0; kt < 15; ++kt) {
    stageA(kt + 1);                 // 2 gload_lds in flight
    loadB(kt + 1, bnext);           // 4 reg loads in flight
    // compute tile kt: 4 ds_read_b128 (A) + 16 MFMA
    {
      const char* Abuf = lds + ((kt & 1) << 13);
      bf16x8 af[4];
#pragma unroll
      for (int mf = 0; mf < 4; ++mf) {
        int r = (wm << 6) + (mf << 4) + lr;
        af[mf] = *reinterpret_cast<const bf16x8*>(Abuf + (r << 6) + ((lk ^ ((r >> 1) & 3)) << 4));
      }
      __builtin_amdgcn_s_setprio(1);
#pragma unroll
      for (int mf = 0; mf < 4; ++mf)
#pragma unroll
        for (int nf = 0; nf < 4; ++nf)
          acc[mf][nf] = __builtin_amdgcn_mfma_f32_16x16x32_bf16(af[mf], bcur[nf], acc[mf][nf], 0, 0, 0);
      __builtin_amdgcn_s_setprio(0);
    }
    asm volatile("s_waitcnt vmcnt(0)" ::: "memory");  // A(kt+1) landed, B(kt+1) in regs
    __builtin_amdgcn_s_barrier();
#pragma unroll
    for (int nf = 0; nf < 4; ++nf) bcur[nf] = bnext[nf];
  }
  // final tile 15
  {
    const char* Abuf = lds + ((15 & 1) << 13);
    bf16x8 af[4];
#pragma unroll
    for (int mf = 0; mf < 4; ++mf) {
      int r = (wm << 6) + (mf << 4) + lr;
      af[mf] = *reinterpret_cast<const bf16x8*>(Abuf + (r << 6) + ((lk ^ ((r >> 1) & 3)) << 4));
    }
#pragma unroll
    for (int mf = 0; mf < 4; ++mf)
#pragma unroll
      for (int nf = 0; nf < 4; ++nf)
        acc[mf][nf] = __builtin_amdgcn_mfma_f32_16x16x32_bf16(af[mf], bcur[nf], acc[mf][nf], 0, 0, 0);
  }
  __builtin_amdgcn_s_barrier();    // all A reads done before LDS reuse

  if (EPI == 0) {
    // ---- epilogue: LDS-bounce (8KB/wave) then coalesced 16B stores ----
    char* ep = lds + (w << 13);    // [64 rows][64 cols] bf16, chunk-XOR
    int gc0 = col0 + (wn << 6);
    int part = gc0 >> 9;           // 0=q 1=k 2=v (uniform per wave)
    int hh = (gc0 & 511) >> 6;
    unsigned short* dst = (part == 0) ? oq : (part == 1) ? okk : ov;
    float bvv[4], rbv[4];
#pragma unroll
    for (int nf = 0; nf < 4; ++nf) {
      int cc = (nf << 4) + lr;
      bvv[nf] = bias[gc0 + cc];
      rbv[nf] = (part == 0) ? brw[(gc0 & 511) + cc] : 0.f;
    }
#pragma unroll
    for (int mf = 0; mf < 4; ++mf) {
#pragma unroll
      for (int nf = 0; nf < 4; ++nf) {
        int cc = (nf << 4) + lr;
#pragma unroll
        for (int j = 0; j < 4; ++j) {
          int r = (mf << 4) + (lk << 2) + j;   // 0..63 within wave rows
          float v = acc[mf][nf][j] + bvv[nf];
          if (part == 0) v = v * 0.125f + rbv[nf];
          int byte = (r << 7) + ((((cc >> 3) ^ (r & 7))) << 4) + ((cc & 7) << 1);
          *reinterpret_cast<unsigned short*>(ep + byte) = f2bf(v);
        }
      }
    }
    asm volatile("s_waitcnt lgkmcnt(0)" ::: "memory");
    __builtin_amdgcn_sched_barrier(0);
    int b0 = row0 >> 11;
    size_t base = (size_t)(b0 * 8 + hh) * 2048;
#pragma unroll
    for (int i = 0; i < 8; ++i) {
      int rr = (i << 3) + (lane >> 3);
      int ch = lane & 7;
      int byte = (rr << 7) + ((ch ^ (rr & 7)) << 4);
      u16x8 val = *reinterpret_cast<const u16x8*>(ep + byte);
      int gl = (row0 + (wm << 6) + rr) & 2047;
      *reinterpret_cast<u16x8*>(dst + ((base + gl) << 6) + (ch << 3)) = val;
    }
  } else {
    // ---- epilogue: f32 C + bias, direct stores ----
#pragma unroll
    for (int mf = 0; mf < 4; ++mf) {
#pragma unroll
      for (int j = 0; j < 4; ++j) {
        int gr = row0 + (wm << 6) + (mf << 4) + (lk << 2) + j;
#pragma unroll
        for (int nf = 0; nf < 4; ++nf) {
          int gc = col0 + (wn << 6) + (nf << 4) + lr;
          of[(size_t)gr * 512 + gc] = acc[mf][nf][j] + bias[gc];
        }
      }
    }
  }
}

// ---------------- banded attention, MFMA version ----------------
// q/k/v: [B*H][2048][64] bf16.  z: [32768][512] bf16 (col = h*64+e).
__global__ __launch_bounds__(256) void k_attn_mfma(
    const unsigned short* __restrict__ qb,
    const unsigned short* __restrict__ kb,
    const unsigned short* __restrict__ vb,
    unsigned short* __restrict__ zb) {
  __shared__ __align__(128) unsigned short smem[13312];  // Vt[0,6656) P[6656,13312)

  int t = threadIdx.x;
  int bh = blockIdx.x >> 5;
  int l0 = (blockIdx.x & 31) << 6;
  size_t slab = (size_t)bh << 17;

#pragma unroll
  for (int i = 0; i < 3; ++i) {
    int kloc = (i << 5) + (t >> 3);
    int c8 = (t & 7) << 3;
    int kg = l0 - 10 + kloc;
    kg = kg < 0 ? 0 : (kg > 2047 ? 2047 : kg);
    u16x8 v = *reinterpret_cast<const u16x8*>(vb + slab + ((size_t)kg << 6) + c8);
#pragma unroll
    for (int e = 0; e < 8; ++e) smem[(c8 + e) * 104 + kloc] = v[e];
  }

  int lane = t & 63;
  int w = t >> 6;
  int lr = lane & 15;
  int lk = lane >> 4;

  const unsigned short* qp = qb + slab + ((size_t)(l0 + (w << 4) + lr) << 6) + (lk << 3);
  bf16x8 qf0 = *reinterpret_cast<const bf16x8*>(qp);
  bf16x8 qf1 = *reinterpret_cast<const bf16x8*>(qp + 32);

  f32x4 sacc[6];
#pragma unroll
  for (int kt = 0; kt < 6; ++kt) {
    int kl = (kt << 4) + lr;
    int kg = l0 - 10 + kl;
    int kgc = kg < 0 ? 0 : (kg > 2047 ? 2047 : kg);
    const unsigned short* kp = kb + slab + ((size_t)kgc << 6) + (lk << 3);
    bf16x8 kf0 = *reinterpret_cast<const bf16x8*>(kp);
    bf16x8 kf1 = *reinterpret_cast<const bf16x8*>(kp + 32);
    f32x4 z4 = {0.f, 0.f, 0.f, 0.f};
    z4 = __builtin_amdgcn_mfma_f32_16x16x32_bf16(qf0, kf0, z4, 0, 0, 0);
    sacc[kt] = __builtin_amdgcn_mfma_f32_16x16x32_bf16(qf1, kf1, z4, 0, 0, 0);
  }

  int qlb = (w << 4) + (lk << 2);
  float p[6][4];
  float minv[4];
#pragma unroll
  for (int j = 0; j < 4; ++j) {
    int ql = qlb + j;
    float mx = -1e30f;
#pragma unroll
    for (int kt = 0; kt < 6; ++kt) {
      int kl = (kt << 4) + lr;
      int kg = l0 - 10 + kl;
      bool valid = (kl >= ql) && (kl <= ql + 20) && (kg >= 0) && (kg < 2048);
      float sv = valid ? sacc[kt][j] : -1e30f;
      p[kt][j] = sv;
      mx = fmaxf(mx, sv);
    }
    mx = fmaxf(mx, __shfl_xor(mx, 1));
    mx = fmaxf(mx, __shfl_xor(mx, 2));
    mx = fmaxf(mx, __shfl_xor(mx, 4));
    mx = fmaxf(mx, __shfl_xor(mx, 8));
    float sum = 0.f;
#pragma unroll
    for (int kt = 0; kt < 6; ++kt) {
      float e = (p[kt][j] > -1e29f) ? __expf(p[kt][j] - mx) : 0.f;
      p[kt][j] = e;
      sum += e;
    }
    sum += __shfl_xor(sum, 1);
    sum += __shfl_xor(sum, 2);
    sum += __shfl_xor(sum, 4);
    sum += __shfl_xor(sum, 8);
    minv[j] = 1.f / sum;
  }

  unsigned short* P = smem + 6656;
#pragma unroll
  for (int j = 0; j < 4; ++j)
#pragma unroll
    for (int kt = 0; kt < 6; ++kt)
      P[(qlb + j) * 104 + (kt << 4) + lr] = f2bf(p[kt][j]);

  __syncthreads();

  f32x4 zacc[4];
#pragma unroll
  for (int dt = 0; dt < 4; ++dt) zacc[dt] = f32x4{0.f, 0.f, 0.f, 0.f};
  bf16x8 pf[3];
#pragma unroll
  for (int s3 = 0; s3 < 3; ++s3)
    pf[s3] = *reinterpret_cast<const bf16x8*>(P + ((w << 4) + lr) * 104 + (s3 << 5) + (lk << 3));
#pragma unroll
  for (int dt = 0; dt < 4; ++dt) {
#pragma unroll
    for (int s3 = 0; s3 < 3; ++s3) {
      bf16x8 vf = *reinterpret_cast<const bf16x8*>(smem + ((dt << 4) + lr) * 104 + (s3 << 5) + (lk << 3));
      zacc[dt] = __builtin_amdgcn_mfma_f32_16x16x32_bf16(pf[s3], vf, zacc[dt], 0, 0, 0);
    }
  }

  __syncthreads();

  unsigned short* ZL = smem;
#pragma unroll
  for (int dt = 0; dt < 4; ++dt)
#pragma unroll
    for (int j = 0; j < 4; ++j)
      ZL[(qlb + j) * 80 + (dt << 4) + lr] = f2bf(zacc[dt][j] * minv[j]);
  asm volatile("s_waitcnt lgkmcnt(0)" ::: "memory");
  __builtin_amdgcn_sched_barrier(0);

  int b = bh >> 3, h = bh & 7;
#pragma unroll
  for (int i = 0; i < 2; ++i) {
    int rr = (w << 4) + (i << 3) + (lane >> 3);
    int ch = (lane & 7) << 3;
    u16x8 val = *reinterpret_cast<const u16x8*>(ZL + rr * 80 + ch);
    size_t orow = (size_t)(b * 2048 + l0 + rr);
    *reinterpret_cast<u16x8*>(zb + (orow << 9) + (h << 6) + ch) = val;
  }
}

// ---------------- launch ----------------

extern "C" void kernel_launch(void* const* d_in, const int* in_sizes, int n_in,
                              void* d_out, int out_size, void* d_ws, size_t ws_size,
                              hipStream_t stream) {
  (void)in_sizes; (void)n_in; (void)out_size; (void)ws_size;
  const float* x    = (const float*)d_in[0];
  const float* Wqkv = (const float*)d_in[1];
  const float* bqkv = (const float*)d_in[2];
  const float* brw  = (const float*)d_in[3];
  const float* Wout = (const float*)d_in[4];
  const float* bout = (const float*)d_in[5];
  float* out = (float*)d_out;

  char* ws = (char*)d_ws;
  unsigned short* xb  = (unsigned short*)(ws);
  unsigned short* wqT = (unsigned short*)(ws + 33554432);
  unsigned short* woT = (unsigned short*)(ws + 35127296);
  unsigned short* qs  = (unsigned short*)(ws + 35651584);
  unsigned short* kbf = (unsigned short*)(ws + 69206016);
  unsigned short* vbf = (unsigned short*)(ws + 102760448);
  unsigned short* zb  = xb;  // safe reuse: x_bf only needed by GEMM1

  k_cvt_x<<<2048, 256, 0, stream>>>(x, xb, 16777216 / 4);
  k_cvt_wT<<<768, 256, 0, stream>>>(Wqkv, wqT, 512, 1536);
  k_cvt_wT<<<256, 256, 0, stream>>>(Wout, woT, 512, 512);
  k_gemm128<0><<<3072, 256, 0, stream>>>(xb, wqT, bqkv, brw, qs, kbf, vbf, nullptr, 12);
  k_attn_mfma<<<4096, 256, 0, stream>>>(qs, kbf, vbf, zb);
  k_gemm128<1><<<1024, 256, 0, stream>>>(zb, woT, bout, nullptr, nullptr, nullptr, nullptr, out, 4);
}

// Round 11
// 151.194 us; speedup vs baseline: 1.3952x; 1.3952x over previous
//
#include <hip/hip_runtime.h>
#include <stdint.h>

typedef __bf16 bf16x8 __attribute__((ext_vector_type(8)));
typedef float f32x4 __attribute__((ext_vector_type(4)));
typedef unsigned short u16x8 __attribute__((ext_vector_type(8)));

__device__ __forceinline__ unsigned short f2bf(float f) {
  uint32_t u = __builtin_bit_cast(uint32_t, f);
  u += 0x7FFFu + ((u >> 16) & 1u);   // RNE
  return (unsigned short)(u >> 16);
}
__device__ __forceinline__ float bf2f(unsigned short h) {
  uint32_t u = ((uint32_t)h) << 16;
  return __builtin_bit_cast(float, u);
}

__device__ __forceinline__ void gload_lds16(const void* g, void* l) {
  __builtin_amdgcn_global_load_lds(
      (const __attribute__((address_space(1))) uint32_t*)g,
      (__attribute__((address_space(3))) uint32_t*)l,
      16, 0, 0);
}

// ---------------- convert kernels ----------------

__global__ __launch_bounds__(256) void k_cvt_x(const float* __restrict__ x,
                                               unsigned short* __restrict__ xb, int n4) {
  int stride = gridDim.x * blockDim.x;
  for (int i = blockIdx.x * blockDim.x + threadIdx.x; i < n4; i += stride) {
    float4 v = reinterpret_cast<const float4*>(x)[i];
    ushort4 o;
    o.x = f2bf(v.x); o.y = f2bf(v.y); o.z = f2bf(v.z); o.w = f2bf(v.w);
    reinterpret_cast<ushort4*>(xb)[i] = o;
  }
}

// w: [K][N] f32  ->  wt: [N][K] bf16  (transpose + convert)
__global__ __launch_bounds__(256) void k_cvt_wT(const float* __restrict__ w,
                                                unsigned short* __restrict__ wt, int K, int N) {
  int total = K * N;
  int stride = gridDim.x * blockDim.x;
  for (int i = blockIdx.x * blockDim.x + threadIdx.x; i < total; i += stride) {
    int n = i / K;
    int k = i - n * K;
    wt[i] = f2bf(w[(size_t)k * N + n]);
  }
}

// ---- GEMM 256x128, BK=32, TRIPLE-buffered, counted-vmcnt (r8 schedule) ----
// C[M,N] = A[M,512] * Bt[N,512]^T. 8 waves (4Mx2N), wave-tile 64x64
// (per-wave schedule IDENTICAL to r8's proven 77.5us kernel; only BM doubled).
// Mechanisms vs r8: (a) half the blocks -> half total prologue/epilogue
// overhead (~13% of GEMM1 time at K=512); (b) LDS 3 bufs x 24KB = 72KB ->
// 2 blocks/CU x 8 waves = 16 waves/CU (vs 12).
// Stage tile kt+2 during kt; tile-end s_waitcnt vmcnt(3) (kt+1's 3 loads
// done; kt+2's 3 stay in flight across the barrier — never drains) + barrier.
// Chunk swizzle slot^=(row>>1)&3 on BOTH stage source and ds_read (rule #21).
// EPI==0: qkv epilogue (bf16 LDS-bounce scatter); EPI==1: f32 C + bias.
template <int EPI>
__global__ __launch_bounds__(512, 4) void k_gemm256x128(
    const unsigned short* __restrict__ A,
    const unsigned short* __restrict__ Bt,
    const float* __restrict__ bias,
    const float* __restrict__ brw,
    unsigned short* __restrict__ oq,
    unsigned short* __restrict__ okk,
    unsigned short* __restrict__ ov,
    float* __restrict__ of,
    int Ntiles) {
  __shared__ __align__(128) char lds[73728];  // buf b at b*24K: A 16KB + B 8KB

  int cpx = gridDim.x >> 3;
  int bid = (blockIdx.x & 7) * cpx + (blockIdx.x >> 3);
  int bm = bid / Ntiles;
  int bn = bid - bm * Ntiles;
  int row0 = bm << 8;
  int col0 = bn << 7;
  int t = threadIdx.x;
  int lane = t & 63;
  int w = t >> 6;        // wave 0..7
  int wm = w >> 1;       // 0..3  (M quadrant)
  int wn = w & 1;        // 0..1  (N half)
  int lr = lane & 15;
  int lk = lane >> 4;    // k-chunk 0..3 (BK=32: 4 x 16B chunks per row)

  const unsigned short* Ab = A + (size_t)row0 * 512;
  const unsigned short* Bb = Bt + (size_t)col0 * 512;

  f32x4 acc[4][4];
#pragma unroll
  for (int i = 0; i < 4; ++i)
#pragma unroll
    for (int j = 0; j < 4; ++j) acc[i][j] = f32x4{0.f, 0.f, 0.f, 0.f};

  // stage K-tile kt into buffer b: 3 gloads/thread (2 A + 1 B)
  auto stage = [&](int kt, int b) {
    int k0 = kt << 5;
    char* base = lds + b * 24576;
#pragma unroll
    for (int i = 0; i < 2; ++i) {     // A: 1024 chunks (256 rows x 4 slots)
      int o = (i << 9) + t;
      int row = o >> 2;               // 0..255
      int slot = o & 3;
      int gk = k0 + ((slot ^ ((row >> 1) & 3)) << 3);
      gload_lds16(Ab + (size_t)row * 512 + gk, base + (o << 4));
    }
    {                                  // B: 512 chunks (128 rows x 4 slots)
      int o = t;
      int row = o >> 2;                // 0..127
      int slot = o & 3;
      int gk = k0 + ((slot ^ ((row >> 1) & 3)) << 3);
      gload_lds16(Bb + (size_t)row * 512 + gk, base + 16384 + (o << 4));
    }
  };

  // compute K-tile in buffer b (8 ds_read_b128 + 16 MFMA), maybe stage kt+2
  auto tile = [&](int b, int ktpf, int bpf, bool pf) {
    const char* Abuf = lds + b * 24576;
    const char* Bbuf = Abuf + 16384;
    bf16x8 af[4], bfs[4];
#pragma unroll
    for (int nf = 0; nf < 4; ++nf) {
      int r = (wn << 6) + (nf << 4) + lr;
      bfs[nf] = *reinterpret_cast<const bf16x8*>(Bbuf + (r << 6) + ((lk ^ ((r >> 1) & 3)) << 4));
    }
#pragma unroll
    for (int mf = 0; mf < 4; ++mf) {
      int r = (wm << 6) + (mf << 4) + lr;
      af[mf] = *reinterpret_cast<const bf16x8*>(Abuf + (r << 6) + ((lk ^ ((r >> 1) & 3)) << 4));
    }
    if (pf) stage(ktpf, bpf);
    __builtin_amdgcn_s_setprio(1);
#pragma unroll
    for (int mf = 0; mf < 4; ++mf)
#pragma unroll
      for (int nf = 0; nf < 4; ++nf)
        acc[mf][nf] = __builtin_amdgcn_mfma_f32_16x16x32_bf16(af[mf], bfs[nf], acc[mf][nf], 0, 0, 0);
    __builtin_amdgcn_s_setprio(0);
  };

  // prologue: stage tiles 0,1; wait tile 0 (tile 1's 3 loads in flight)
  stage(0, 0);
  stage(1, 1);
  asm volatile("s_waitcnt vmcnt(3)" ::: "memory");
  __builtin_amdgcn_s_barrier();

  int cb = 0;
#pragma unroll 1
  for (int kt = 0; kt < 14; ++kt) {
    int pb = cb + 2; if (pb >= 3) pb -= 3;
    tile(cb, kt + 2, pb, true);
    // kt+1's 3 loads are oldest of 6 outstanding; kt+2 stays in flight
    asm volatile("s_waitcnt vmcnt(3)" ::: "memory");
    __builtin_amdgcn_s_barrier();
    ++cb; if (cb >= 3) cb -= 3;
  }
  tile(cb, 0, 0, false);               // kt = 14
  asm volatile("s_waitcnt vmcnt(0)" ::: "memory");
  __builtin_amdgcn_s_barrier();
  ++cb; if (cb >= 3) cb -= 3;
  tile(cb, 0, 0, false);               // kt = 15
  __builtin_amdgcn_s_barrier();        // all reads done before LDS reuse

  if (EPI == 0) {
    // ---- epilogue: LDS-bounce (8KB/wave) then coalesced 16B stores ----
    char* ep = lds + (w << 13);        // 8 waves x 8KB = 64KB <= 72KB
    int gc0 = col0 + (wn << 6);
    int part = gc0 >> 9;               // 0=q 1=k 2=v (uniform per wave)
    int hh = (gc0 & 511) >> 6;
    unsigned short* dst = (part == 0) ? oq : (part == 1) ? okk : ov;
    float bvv[4], rbv[4];
#pragma unroll
    for (int nf = 0; nf < 4; ++nf) {
      int cc = (nf << 4) + lr;
      bvv[nf] = bias[gc0 + cc];
      rbv[nf] = (part == 0) ? brw[(gc0 & 511) + cc] : 0.f;
    }
#pragma unroll
    for (int mf = 0; mf < 4; ++mf) {
#pragma unroll
      for (int nf = 0; nf < 4; ++nf) {
        int cc = (nf << 4) + lr;
#pragma unroll
        for (int j = 0; j < 4; ++j) {
          int r = (mf << 4) + (lk << 2) + j;   // 0..63 within wave rows
          float v = acc[mf][nf][j] + bvv[nf];
          if (part == 0) v = v * 0.125f + rbv[nf];
          int byte = (r << 7) + ((((cc >> 3) ^ (r & 7))) << 4) + ((cc & 7) << 1);
          *reinterpret_cast<unsigned short*>(ep + byte) = f2bf(v);
        }
      }
    }
    asm volatile("s_waitcnt lgkmcnt(0)" ::: "memory");
    __builtin_amdgcn_sched_barrier(0);
    int b0 = row0 >> 11;
    size_t base = (size_t)(b0 * 8 + hh) * 2048;
#pragma unroll
    for (int i = 0; i < 8; ++i) {
      int rr = (i << 3) + (lane >> 3);
      int ch = lane & 7;
      int byte = (rr << 7) + ((ch ^ (rr & 7)) << 4);
      u16x8 val = *reinterpret_cast<const u16x8*>(ep + byte);
      int gl = (row0 + (wm << 6) + rr) & 2047;
      *reinterpret_cast<u16x8*>(dst + ((base + gl) << 6) + (ch << 3)) = val;
    }
  } else {
    // ---- epilogue: f32 C + bias, direct stores ----
#pragma unroll
    for (int mf = 0; mf < 4; ++mf) {
#pragma unroll
      for (int j = 0; j < 4; ++j) {
        int gr = row0 + (wm << 6) + (mf << 4) + (lk << 2) + j;
#pragma unroll
        for (int nf = 0; nf < 4; ++nf) {
          int gc = col0 + (wn << 6) + (nf << 4) + lr;
          of[(size_t)gr * 512 + gc] = acc[mf][nf][j] + bias[gc];
        }
      }
    }
  }
}

// ---------------- banded attention, MFMA version ----------------
// q/k/v: [B*H][2048][64] bf16.  z: [32768][512] bf16 (col = h*64+e).
__global__ __launch_bounds__(256) void k_attn_mfma(
    const unsigned short* __restrict__ qb,
    const unsigned short* __restrict__ kb,
    const unsigned short* __restrict__ vb,
    unsigned short* __restrict__ zb) {
  __shared__ __align__(128) unsigned short smem[13312];  // Vt[0,6656) P[6656,13312)

  int t = threadIdx.x;
  int bh = blockIdx.x >> 5;
  int l0 = (blockIdx.x & 31) << 6;
  size_t slab = (size_t)bh << 17;

#pragma unroll
  for (int i = 0; i < 3; ++i) {
    int kloc = (i << 5) + (t >> 3);
    int c8 = (t & 7) << 3;
    int kg = l0 - 10 + kloc;
    kg = kg < 0 ? 0 : (kg > 2047 ? 2047 : kg);
    u16x8 v = *reinterpret_cast<const u16x8*>(vb + slab + ((size_t)kg << 6) + c8);
#pragma unroll
    for (int e = 0; e < 8; ++e) smem[(c8 + e) * 104 + kloc] = v[e];
  }

  int lane = t & 63;
  int w = t >> 6;
  int lr = lane & 15;
  int lk = lane >> 4;

  const unsigned short* qp = qb + slab + ((size_t)(l0 + (w << 4) + lr) << 6) + (lk << 3);
  bf16x8 qf0 = *reinterpret_cast<const bf16x8*>(qp);
  bf16x8 qf1 = *reinterpret_cast<const bf16x8*>(qp + 32);

  f32x4 sacc[6];
#pragma unroll
  for (int kt = 0; kt < 6; ++kt) {
    int kl = (kt << 4) + lr;
    int kg = l0 - 10 + kl;
    int kgc = kg < 0 ? 0 : (kg > 2047 ? 2047 : kg);
    const unsigned short* kp = kb + slab + ((size_t)kgc << 6) + (lk << 3);
    bf16x8 kf0 = *reinterpret_cast<const bf16x8*>(kp);
    bf16x8 kf1 = *reinterpret_cast<const bf16x8*>(kp + 32);
    f32x4 z4 = {0.f, 0.f, 0.f, 0.f};
    z4 = __builtin_amdgcn_mfma_f32_16x16x32_bf16(qf0, kf0, z4, 0, 0, 0);
    sacc[kt] = __builtin_amdgcn_mfma_f32_16x16x32_bf16(qf1, kf1, z4, 0, 0, 0);
  }

  int qlb = (w << 4) + (lk << 2);
  float p[6][4];
  float minv[4];
#pragma unroll
  for (int j = 0; j < 4; ++j) {
    int ql = qlb + j;
    float mx = -1e30f;
#pragma unroll
    for (int kt = 0; kt < 6; ++kt) {
      int kl = (kt << 4) + lr;
      int kg = l0 - 10 + kl;
      bool valid = (kl >= ql) && (kl <= ql + 20) && (kg >= 0) && (kg < 2048);
      float sv = valid ? sacc[kt][j] : -1e30f;
      p[kt][j] = sv;
      mx = fmaxf(mx, sv);
    }
    mx = fmaxf(mx, __shfl_xor(mx, 1));
    mx = fmaxf(mx, __shfl_xor(mx, 2));
    mx = fmaxf(mx, __shfl_xor(mx, 4));
    mx = fmaxf(mx, __shfl_xor(mx, 8));
    float sum = 0.f;
#pragma unroll
    for (int kt = 0; kt < 6; ++kt) {
      float e = (p[kt][j] > -1e29f) ? __expf(p[kt][j] - mx) : 0.f;
      p[kt][j] = e;
      sum += e;
    }
    sum += __shfl_xor(sum, 1);
    sum += __shfl_xor(sum, 2);
    sum += __shfl_xor(sum, 4);
    sum += __shfl_xor(sum, 8);
    minv[j] = 1.f / sum;
  }

  unsigned short* P = smem + 6656;
#pragma unroll
  for (int j = 0; j < 4; ++j)
#pragma unroll
    for (int kt = 0; kt < 6; ++kt)
      P[(qlb + j) * 104 + (kt << 4) + lr] = f2bf(p[kt][j]);

  __syncthreads();

  f32x4 zacc[4];
#pragma unroll
  for (int dt = 0; dt < 4; ++dt) zacc[dt] = f32x4{0.f, 0.f, 0.f, 0.f};
  bf16x8 pf[3];
#pragma unroll
  for (int s3 = 0; s3 < 3; ++s3)
    pf[s3] = *reinterpret_cast<const bf16x8*>(P + ((w << 4) + lr) * 104 + (s3 << 5) + (lk << 3));
#pragma unroll
  for (int dt = 0; dt < 4; ++dt) {
#pragma unroll
    for (int s3 = 0; s3 < 3; ++s3) {
      bf16x8 vf = *reinterpret_cast<const bf16x8*>(smem + ((dt << 4) + lr) * 104 + (s3 << 5) + (lk << 3));
      zacc[dt] = __builtin_amdgcn_mfma_f32_16x16x32_bf16(pf[s3], vf, zacc[dt], 0, 0, 0);
    }
  }

  __syncthreads();

  unsigned short* ZL = smem;
#pragma unroll
  for (int dt = 0; dt < 4; ++dt)
#pragma unroll
    for (int j = 0; j < 4; ++j)
      ZL[(qlb + j) * 80 + (dt << 4) + lr] = f2bf(zacc[dt][j] * minv[j]);
  asm volatile("s_waitcnt lgkmcnt(0)" ::: "memory");
  __builtin_amdgcn_sched_barrier(0);

  int b = bh >> 3, h = bh & 7;
#pragma unroll
  for (int i = 0; i < 2; ++i) {
    int rr = (w << 4) + (i << 3) + (lane >> 3);
    int ch = (lane & 7) << 3;
    u16x8 val = *reinterpret_cast<const u16x8*>(ZL + rr * 80 + ch);
    size_t orow = (size_t)(b * 2048 + l0 + rr);
    *reinterpret_cast<u16x8*>(zb + (orow << 9) + (h << 6) + ch) = val;
  }
}

// ---------------- launch ----------------

extern "C" void kernel_launch(void* const* d_in, const int* in_sizes, int n_in,
                              void* d_out, int out_size, void* d_ws, size_t ws_size,
                              hipStream_t stream) {
  (void)in_sizes; (void)n_in; (void)out_size; (void)ws_size;
  const float* x    = (const float*)d_in[0];
  const float* Wqkv = (const float*)d_in[1];
  const float* bqkv = (const float*)d_in[2];
  const float* brw  = (const float*)d_in[3];
  const float* Wout = (const float*)d_in[4];
  const float* bout = (const float*)d_in[5];
  float* out = (float*)d_out;

  char* ws = (char*)d_ws;
  unsigned short* xb  = (unsigned short*)(ws);
  unsigned short* wqT = (unsigned short*)(ws + 33554432);
  unsigned short* woT = (unsigned short*)(ws + 35127296);
  unsigned short* qs  = (unsigned short*)(ws + 35651584);
  unsigned short* kbf = (unsigned short*)(ws + 69206016);
  unsigned short* vbf = (unsigned short*)(ws + 102760448);
  unsigned short* zb  = xb;  // safe reuse: x_bf only needed by GEMM1

  k_cvt_x<<<2048, 256, 0, stream>>>(x, xb, 16777216 / 4);
  k_cvt_wT<<<768, 256, 0, stream>>>(Wqkv, wqT, 512, 1536);
  k_cvt_wT<<<256, 256, 0, stream>>>(Wout, woT, 512, 512);
  k_gemm256x128<0><<<1536, 512, 0, stream>>>(xb, wqT, bqkv, brw, qs, kbf, vbf, nullptr, 12);
  k_attn_mfma<<<4096, 256, 0, stream>>>(qs, kbf, vbf, zb);
  k_gemm256x128<1><<<512, 512, 0, stream>>>(zb, woT, bout, nullptr, nullptr, nullptr, nullptr, out, 4);
}

// Round 12
// 147.006 us; speedup vs baseline: 1.4350x; 1.0285x over previous
//
#include <hip/hip_runtime.h>
#include <stdint.h>

typedef __bf16 bf16x8 __attribute__((ext_vector_type(8)));
typedef float f32x4 __attribute__((ext_vector_type(4)));
typedef unsigned short u16x8 __attribute__((ext_vector_type(8)));

__device__ __forceinline__ unsigned short f2bf(float f) {
  uint32_t u = __builtin_bit_cast(uint32_t, f);
  u += 0x7FFFu + ((u >> 16) & 1u);   // RNE
  return (unsigned short)(u >> 16);
}
__device__ __forceinline__ float bf2f(unsigned short h) {
  uint32_t u = ((uint32_t)h) << 16;
  return __builtin_bit_cast(float, u);
}

__device__ __forceinline__ void gload_lds16(const void* g, void* l) {
  __builtin_amdgcn_global_load_lds(
      (const __attribute__((address_space(1))) uint32_t*)g,
      (__attribute__((address_space(3))) uint32_t*)l,
      16, 0, 0);
}

// ---------------- fused convert kernel (one launch) ----------------
// blocks [0,2048): x f32 -> xb bf16 (float4-vectorized)
// blocks [2048,2816): Wqkv [512][1536] -> wqT [1536][512] bf16
// blocks [2816,3072): Wout [512][512] -> woT [512][512] bf16
__global__ __launch_bounds__(256) void k_cvt_all(
    const float* __restrict__ x, const float* __restrict__ Wqkv,
    const float* __restrict__ Wout, unsigned short* __restrict__ xb,
    unsigned short* __restrict__ wqT, unsigned short* __restrict__ woT) {
  int b = blockIdx.x;
  if (b < 2048) {
    int stride = 2048 * 256;
    for (int i = b * 256 + threadIdx.x; i < 4194304; i += stride) {
      float4 v = reinterpret_cast<const float4*>(x)[i];
      ushort4 o;
      o.x = f2bf(v.x); o.y = f2bf(v.y); o.z = f2bf(v.z); o.w = f2bf(v.w);
      reinterpret_cast<ushort4*>(xb)[i] = o;
    }
  } else if (b < 2816) {
    int stride = 768 * 256;
    for (int i = (b - 2048) * 256 + threadIdx.x; i < 786432; i += stride) {
      int n = i >> 9;                 // / 512
      int k = i & 511;
      wqT[i] = f2bf(Wqkv[(size_t)k * 1536 + n]);
    }
  } else {
    int stride = 256 * 256;
    for (int i = (b - 2816) * 256 + threadIdx.x; i < 262144; i += stride) {
      int n = i >> 9;
      int k = i & 511;
      woT[i] = f2bf(Wout[(size_t)k * 512 + n]);
    }
  }
}

// ---- GEMM 256x128, BK=32, TRIPLE-buffered, counted-vmcnt (r11 schedule) ----
// C[M,N] = A[M,512] * Bt[N,512]^T. 8 waves (4Mx2N), wave-tile 64x64.
// r11 proven structure (71us GEMM1) — UNCHANGED schedule. This round's only
// edit: staging address math hoisted out of the K-loop (3 per-thread global
// base pointers + LDS dest offsets precomputed; per-stage = base + kt*64B).
// Stage tile kt+2 during kt; tile-end s_waitcnt vmcnt(3) (kt+1's 3 loads
// done; kt+2's 3 stay in flight across the barrier — never drains) + barrier.
// Chunk swizzle slot^=(row>>1)&3 on BOTH stage source and ds_read (rule #21).
// EPI==0: qkv epilogue (bf16 LDS-bounce scatter); EPI==1: f32 C + bias.
template <int EPI>
__global__ __launch_bounds__(512, 4) void k_gemm256x128(
    const unsigned short* __restrict__ A,
    const unsigned short* __restrict__ Bt,
    const float* __restrict__ bias,
    const float* __restrict__ brw,
    unsigned short* __restrict__ oq,
    unsigned short* __restrict__ okk,
    unsigned short* __restrict__ ov,
    float* __restrict__ of,
    int Ntiles) {
  __shared__ __align__(128) char lds[73728];  // buf b at b*24K: A 16KB + B 8KB

  int cpx = gridDim.x >> 3;
  int bid = (blockIdx.x & 7) * cpx + (blockIdx.x >> 3);
  int bm = bid / Ntiles;
  int bn = bid - bm * Ntiles;
  int row0 = bm << 8;
  int col0 = bn << 7;
  int t = threadIdx.x;
  int lane = t & 63;
  int w = t >> 6;        // wave 0..7
  int wm = w >> 1;       // 0..3  (M quadrant)
  int wn = w & 1;        // 0..1  (N half)
  int lr = lane & 15;
  int lk = lane >> 4;    // k-chunk 0..3

  const unsigned short* Ab = A + (size_t)row0 * 512;
  const unsigned short* Bb = Bt + (size_t)col0 * 512;

  // ---- hoisted staging geometry (loop-invariant) ----
  const unsigned short *gA0, *gA1, *gB0;
  int dA0, dA1, dB0;
  {
    int o = t, row = o >> 2, slot = o & 3;
    int sw = (slot ^ ((row >> 1) & 3)) << 3;
    gA0 = Ab + (size_t)row * 512 + sw;
    gB0 = Bb + (size_t)row * 512 + sw;      // B rows 0..127 (t<512 -> row<128)
    dA0 = o << 4;
    dB0 = 16384 + (o << 4);
    int o1 = 512 + t, row1 = o1 >> 2, slot1 = o1 & 3;
    gA1 = Ab + (size_t)row1 * 512 + ((slot1 ^ ((row1 >> 1) & 3)) << 3);
    dA1 = o1 << 4;
  }

  f32x4 acc[4][4];
#pragma unroll
  for (int i = 0; i < 4; ++i)
#pragma unroll
    for (int j = 0; j < 4; ++j) acc[i][j] = f32x4{0.f, 0.f, 0.f, 0.f};

  // stage K-tile kt into buffer b: 3 gloads/thread (2 A + 1 B), addr = base+kt*32elem
  auto stage = [&](int kt, int b) {
    int k0 = kt << 5;
    char* base = lds + b * 24576;
    gload_lds16(gA0 + k0, base + dA0);
    gload_lds16(gA1 + k0, base + dA1);
    gload_lds16(gB0 + k0, base + dB0);
  };

  // compute K-tile in buffer b (8 ds_read_b128 + 16 MFMA), maybe stage kt+2
  auto tile = [&](int b, int ktpf, int bpf, bool pf) {
    const char* Abuf = lds + b * 24576;
    const char* Bbuf = Abuf + 16384;
    bf16x8 af[4], bfs[4];
#pragma unroll
    for (int nf = 0; nf < 4; ++nf) {
      int r = (wn << 6) + (nf << 4) + lr;
      bfs[nf] = *reinterpret_cast<const bf16x8*>(Bbuf + (r << 6) + ((lk ^ ((r >> 1) & 3)) << 4));
    }
#pragma unroll
    for (int mf = 0; mf < 4; ++mf) {
      int r = (wm << 6) + (mf << 4) + lr;
      af[mf] = *reinterpret_cast<const bf16x8*>(Abuf + (r << 6) + ((lk ^ ((r >> 1) & 3)) << 4));
    }
    if (pf) stage(ktpf, bpf);
    __builtin_amdgcn_s_setprio(1);
#pragma unroll
    for (int mf = 0; mf < 4; ++mf)
#pragma unroll
      for (int nf = 0; nf < 4; ++nf)
        acc[mf][nf] = __builtin_amdgcn_mfma_f32_16x16x32_bf16(af[mf], bfs[nf], acc[mf][nf], 0, 0, 0);
    __builtin_amdgcn_s_setprio(0);
  };

  // prologue: stage tiles 0,1; wait tile 0 (tile 1's 3 loads in flight)
  stage(0, 0);
  stage(1, 1);
  asm volatile("s_waitcnt vmcnt(3)" ::: "memory");
  __builtin_amdgcn_s_barrier();

  int cb = 0;
#pragma unroll 1
  for (int kt = 0; kt < 14; ++kt) {
    int pb = cb + 2; if (pb >= 3) pb -= 3;
    tile(cb, kt + 2, pb, true);
    // kt+1's 3 loads are oldest of 6 outstanding; kt+2 stays in flight
    asm volatile("s_waitcnt vmcnt(3)" ::: "memory");
    __builtin_amdgcn_s_barrier();
    ++cb; if (cb >= 3) cb -= 3;
  }
  tile(cb, 0, 0, false);               // kt = 14
  asm volatile("s_waitcnt vmcnt(0)" ::: "memory");
  __builtin_amdgcn_s_barrier();
  ++cb; if (cb >= 3) cb -= 3;
  tile(cb, 0, 0, false);               // kt = 15
  __builtin_amdgcn_s_barrier();        // all reads done before LDS reuse

  if (EPI == 0) {
    // ---- epilogue: LDS-bounce (8KB/wave) then coalesced 16B stores ----
    char* ep = lds + (w << 13);        // 8 waves x 8KB = 64KB <= 72KB
    int gc0 = col0 + (wn << 6);
    int part = gc0 >> 9;               // 0=q 1=k 2=v (uniform per wave)
    int hh = (gc0 & 511) >> 6;
    unsigned short* dst = (part == 0) ? oq : (part == 1) ? okk : ov;
    float bvv[4], rbv[4];
#pragma unroll
    for (int nf = 0; nf < 4; ++nf) {
      int cc = (nf << 4) + lr;
      bvv[nf] = bias[gc0 + cc];
      rbv[nf] = (part == 0) ? brw[(gc0 & 511) + cc] : 0.f;
    }
#pragma unroll
    for (int mf = 0; mf < 4; ++mf) {
#pragma unroll
      for (int nf = 0; nf < 4; ++nf) {
        int cc = (nf << 4) + lr;
#pragma unroll
        for (int j = 0; j < 4; ++j) {
          int r = (mf << 4) + (lk << 2) + j;   // 0..63 within wave rows
          float v = acc[mf][nf][j] + bvv[nf];
          if (part == 0) v = v * 0.125f + rbv[nf];
          int byte = (r << 7) + ((((cc >> 3) ^ (r & 7))) << 4) + ((cc & 7) << 1);
          *reinterpret_cast<unsigned short*>(ep + byte) = f2bf(v);
        }
      }
    }
    asm volatile("s_waitcnt lgkmcnt(0)" ::: "memory");
    __builtin_amdgcn_sched_barrier(0);
    int b0 = row0 >> 11;
    size_t base = (size_t)(b0 * 8 + hh) * 2048;
#pragma unroll
    for (int i = 0; i < 8; ++i) {
      int rr = (i << 3) + (lane >> 3);
      int ch = lane & 7;
      int byte = (rr << 7) + ((ch ^ (rr & 7)) << 4);
      u16x8 val = *reinterpret_cast<const u16x8*>(ep + byte);
      int gl = (row0 + (wm << 6) + rr) & 2047;
      *reinterpret_cast<u16x8*>(dst + ((base + gl) << 6) + (ch << 3)) = val;
    }
  } else {
    // ---- epilogue: f32 C + bias, direct stores ----
#pragma unroll
    for (int mf = 0; mf < 4; ++mf) {
#pragma unroll
      for (int j = 0; j < 4; ++j) {
        int gr = row0 + (wm << 6) + (mf << 4) + (lk << 2) + j;
#pragma unroll
        for (int nf = 0; nf < 4; ++nf) {
          int gc = col0 + (wn << 6) + (nf << 4) + lr;
          of[(size_t)gr * 512 + gc] = acc[mf][nf][j] + bias[gc];
        }
      }
    }
  }
}

// ---------------- banded attention, MFMA version ----------------
// q/k/v: [B*H][2048][64] bf16.  z: [32768][512] bf16 (col = h*64+e).
__global__ __launch_bounds__(256) void k_attn_mfma(
    const unsigned short* __restrict__ qb,
    const unsigned short* __restrict__ kb,
    const unsigned short* __restrict__ vb,
    unsigned short* __restrict__ zb) {
  __shared__ __align__(128) unsigned short smem[13312];  // Vt[0,6656) P[6656,13312)

  int t = threadIdx.x;
  int bh = blockIdx.x >> 5;
  int l0 = (blockIdx.x & 31) << 6;
  size_t slab = (size_t)bh << 17;

#pragma unroll
  for (int i = 0; i < 3; ++i) {
    int kloc = (i << 5) + (t >> 3);
    int c8 = (t & 7) << 3;
    int kg = l0 - 10 + kloc;
    kg = kg < 0 ? 0 : (kg > 2047 ? 2047 : kg);
    u16x8 v = *reinterpret_cast<const u16x8*>(vb + slab + ((size_t)kg << 6) + c8);
#pragma unroll
    for (int e = 0; e < 8; ++e) smem[(c8 + e) * 104 + kloc] = v[e];
  }

  int lane = t & 63;
  int w = t >> 6;
  int lr = lane & 15;
  int lk = lane >> 4;

  const unsigned short* qp = qb + slab + ((size_t)(l0 + (w << 4) + lr) << 6) + (lk << 3);
  bf16x8 qf0 = *reinterpret_cast<const bf16x8*>(qp);
  bf16x8 qf1 = *reinterpret_cast<const bf16x8*>(qp + 32);

  f32x4 sacc[6];
#pragma unroll
  for (int kt = 0; kt < 6; ++kt) {
    int kl = (kt << 4) + lr;
    int kg = l0 - 10 + kl;
    int kgc = kg < 0 ? 0 : (kg > 2047 ? 2047 : kg);
    const unsigned short* kp = kb + slab + ((size_t)kgc << 6) + (lk << 3);
    bf16x8 kf0 = *reinterpret_cast<const bf16x8*>(kp);
    bf16x8 kf1 = *reinterpret_cast<const bf16x8*>(kp + 32);
    f32x4 z4 = {0.f, 0.f, 0.f, 0.f};
    z4 = __builtin_amdgcn_mfma_f32_16x16x32_bf16(qf0, kf0, z4, 0, 0, 0);
    sacc[kt] = __builtin_amdgcn_mfma_f32_16x16x32_bf16(qf1, kf1, z4, 0, 0, 0);
  }

  int qlb = (w << 4) + (lk << 2);
  float p[6][4];
  float minv[4];
#pragma unroll
  for (int j = 0; j < 4; ++j) {
    int ql = qlb + j;
    float mx = -1e30f;
#pragma unroll
    for (int kt = 0; kt < 6; ++kt) {
      int kl = (kt << 4) + lr;
      int kg = l0 - 10 + kl;
      bool valid = (kl >= ql) && (kl <= ql + 20) && (kg >= 0) && (kg < 2048);
      float sv = valid ? sacc[kt][j] : -1e30f;
      p[kt][j] = sv;
      mx = fmaxf(mx, sv);
    }
    mx = fmaxf(mx, __shfl_xor(mx, 1));
    mx = fmaxf(mx, __shfl_xor(mx, 2));
    mx = fmaxf(mx, __shfl_xor(mx, 4));
    mx = fmaxf(mx, __shfl_xor(mx, 8));
    float sum = 0.f;
#pragma unroll
    for (int kt = 0; kt < 6; ++kt) {
      float e = (p[kt][j] > -1e29f) ? __expf(p[kt][j] - mx) : 0.f;
      p[kt][j] = e;
      sum += e;
    }
    sum += __shfl_xor(sum, 1);
    sum += __shfl_xor(sum, 2);
    sum += __shfl_xor(sum, 4);
    sum += __shfl_xor(sum, 8);
    minv[j] = 1.f / sum;
  }

  unsigned short* P = smem + 6656;
#pragma unroll
  for (int j = 0; j < 4; ++j)
#pragma unroll
    for (int kt = 0; kt < 6; ++kt)
      P[(qlb + j) * 104 + (kt << 4) + lr] = f2bf(p[kt][j]);

  __syncthreads();

  f32x4 zacc[4];
#pragma unroll
  for (int dt = 0; dt < 4; ++dt) zacc[dt] = f32x4{0.f, 0.f, 0.f, 0.f};
  bf16x8 pf[3];
#pragma unroll
  for (int s3 = 0; s3 < 3; ++s3)
    pf[s3] = *reinterpret_cast<const bf16x8*>(P + ((w << 4) + lr) * 104 + (s3 << 5) + (lk << 3));
#pragma unroll
  for (int dt = 0; dt < 4; ++dt) {
#pragma unroll
    for (int s3 = 0; s3 < 3; ++s3) {
      bf16x8 vf = *reinterpret_cast<const bf16x8*>(smem + ((dt << 4) + lr) * 104 + (s3 << 5) + (lk << 3));
      zacc[dt] = __builtin_amdgcn_mfma_f32_16x16x32_bf16(pf[s3], vf, zacc[dt], 0, 0, 0);
    }
  }

  __syncthreads();

  unsigned short* ZL = smem;
#pragma unroll
  for (int dt = 0; dt < 4; ++dt)
#pragma unroll
    for (int j = 0; j < 4; ++j)
      ZL[(qlb + j) * 80 + (dt << 4) + lr] = f2bf(zacc[dt][j] * minv[j]);
  asm volatile("s_waitcnt lgkmcnt(0)" ::: "memory");
  __builtin_amdgcn_sched_barrier(0);

  int b = bh >> 3, h = bh & 7;
#pragma unroll
  for (int i = 0; i < 2; ++i) {
    int rr = (w << 4) + (i << 3) + (lane >> 3);
    int ch = (lane & 7) << 3;
    u16x8 val = *reinterpret_cast<const u16x8*>(ZL + rr * 80 + ch);
    size_t orow = (size_t)(b * 2048 + l0 + rr);
    *reinterpret_cast<u16x8*>(zb + (orow << 9) + (h << 6) + ch) = val;
  }
}

// ---------------- launch ----------------

extern "C" void kernel_launch(void* const* d_in, const int* in_sizes, int n_in,
                              void* d_out, int out_size, void* d_ws, size_t ws_size,
                              hipStream_t stream) {
  (void)in_sizes; (void)n_in; (void)out_size; (void)ws_size;
  const float* x    = (const float*)d_in[0];
  const float* Wqkv = (const float*)d_in[1];
  const float* bqkv = (const float*)d_in[2];
  const float* brw  = (const float*)d_in[3];
  const float* Wout = (const float*)d_in[4];
  const float* bout = (const float*)d_in[5];
  float* out = (float*)d_out;

  char* ws = (char*)d_ws;
  unsigned short* xb  = (unsigned short*)(ws);
  unsigned short* wqT = (unsigned short*)(ws + 33554432);
  unsigned short* woT = (unsigned short*)(ws + 35127296);
  unsigned short* qs  = (unsigned short*)(ws + 35651584);
  unsigned short* kbf = (unsigned short*)(ws + 69206016);
  unsigned short* vbf = (unsigned short*)(ws + 102760448);
  unsigned short* zb  = xb;  // safe reuse: x_bf only needed by GEMM1

  k_cvt_all<<<3072, 256, 0, stream>>>(x, Wqkv, Wout, xb, wqT, woT);
  k_gemm256x128<0><<<1536, 512, 0, stream>>>(xb, wqT, bqkv, brw, qs, kbf, vbf, nullptr, 12);
  k_attn_mfma<<<4096, 256, 0, stream>>>(qs, kbf, vbf, zb);
  k_gemm256x128<1><<<512, 512, 0, stream>>>(zb, woT, bout, nullptr, nullptr, nullptr, nullptr, out, 4);
}